// Round 14
// baseline (241.052 us; speedup 1.0000x reference)
//
#include <hip/hip_runtime.h>
#include <hip/hip_bf16.h>
#include <math.h>

// ---------------- problem constants ----------------
#define NB 32
#define QL 32
#define DL 1024
#define EMB 300
#define EMBP 320            // padded K-dim per tap (zeros 300..319)
#define OD 128
#define KNUM 21
#define VOCAB 50000

typedef short short8 __attribute__((ext_vector_type(8)));
typedef float floatx4 __attribute__((ext_vector_type(4)));

// workspace layout (in float units)
static const size_t WP_OFF  = 0;           // packed bf16 weights: 245760 ushorts = 122880 fl
static const size_t DPK_OFF = 122880;      // packed doc bf16 [32*1024][320] = 5242880 fl
static const size_t QPK_OFF = 5365760;     // packed query bf16 [(1024+2)][320] = 164160 fl
// encoder outputs stored as SPLIT bf16 hi/lo planes
static const size_t QH_OFF  = 5529920;     // qenc hi: 3 * 32*32*128 us = 196608 fl
static const size_t QLO_OFF = 5726528;     // qenc lo
static const size_t DH_OFF  = 5923136;     // denc hi: 3 * 32*1024*128 us = 6291456 fl
static const size_t DLO_OFF = 12214592;    // denc lo
static const size_t ACC_OFF = 18506048;
static const int ACC_SZ = 9 * NB * QL * KNUM;          // 193536

#define QPLANE 131072      // ushorts per z-plane of qenc (32*32*128)
#define DPLANE 4194304     // ushorts per z-plane of denc (32*1024*128)

// combined packed rows: doc (32768) + query (1024) + 2 zero guard rows
#define MROWS (NB * DL + NB * QL)      // 33792 = 264 * 128 exactly
#define MTILES 264
#define CONV_BLOCKS (MTILES * 3)       // 792, divisible by 8 (XCD swizzle bijective)

#define PREPW_N 245760
#define GATHER_N ((MROWS + 2) * 40)

__device__ __constant__ int WPOFF_C[3] = {0, 40960, 122880};

__device__ __forceinline__ void gl_lds16(const ushort* g, char* l) {
    __builtin_amdgcn_global_load_lds(
        (const __attribute__((address_space(1))) unsigned int*)(g),
        (__attribute__((address_space(3))) unsigned int*)(l), 16, 0, 0);
}

__device__ __forceinline__ ushort bf16_bits(float f) {
    __hip_bfloat16 h = __float2bfloat16(f);
    return *reinterpret_cast<ushort*>(&h);
}

// ---------------- fused producer: weights->bf16 pack + token-row gather/pack ----------------
__global__ void gather_prep(const float* __restrict__ emb,
                            const int* __restrict__ dids, const int* __restrict__ qids,
                            const float* __restrict__ w1, const float* __restrict__ w2,
                            const float* __restrict__ w3,
                            ushort* __restrict__ dpk, ushort* __restrict__ qpk,
                            ushort* __restrict__ wp) {
    int idx = blockIdx.x * 256 + threadIdx.x;
    if (idx < PREPW_N) {
        // ---- weights -> bf16, layout [o][j*320+c] ----
        const float* src;
        int k, rel, base;
        if (idx < 40960)        { k = 1; rel = idx;          src = w1; base = 0; }
        else if (idx < 122880)  { k = 2; rel = idx - 40960;  src = w2; base = 40960; }
        else                    { k = 3; rel = idx - 122880; src = w3; base = 122880; }
        int kd = 320 * k;
        int o = rel / kd;
        int jc = rel - o * kd;
        int j = jc / EMBP;
        int c = jc - j * EMBP;
        float f = (c < EMB) ? src[(o * EMB + c) * k + j] : 0.f;
        wp[base + rel] = bf16_bits(f);
        return;
    }
    idx -= PREPW_N;
    if (idx >= GATHER_N) return;
    // ---- gather token rows: fp32 emb -> packed bf16 [row][320] (doc + query + 2 zero rows) ----
    const int DROWS = NB * DL;
    int r = idx / 40;
    int c0 = (idx - r * 40) * 8;
    int rid;
    ushort* dst;
    if (r < DROWS) { rid = dids[r]; dst = dpk + (size_t)r * EMBP; }
    else if (r < DROWS + NB * QL) { rid = qids[r - DROWS]; dst = qpk + (size_t)(r - DROWS) * EMBP; }
    else {
        uint4 zz = {0u, 0u, 0u, 0u};
        *reinterpret_cast<uint4*>(qpk + (size_t)(r - DROWS) * EMBP + c0) = zz;
        return;
    }
    const float* erow = emb + (size_t)rid * EMB;
    ushort v[8];
    if (c0 + 8 <= EMB) {
        float4 f0 = *reinterpret_cast<const float4*>(erow + c0);
        float4 f1 = *reinterpret_cast<const float4*>(erow + c0 + 4);
        float fv[8] = {f0.x, f0.y, f0.z, f0.w, f1.x, f1.y, f1.z, f1.w};
#pragma unroll
        for (int i = 0; i < 8; ++i) v[i] = bf16_bits(fv[i]);
    } else {
#pragma unroll
        for (int i = 0; i < 8; ++i) {
            int c = c0 + i;
            v[i] = bf16_bits((c < EMB) ? erow[c] : 0.f);
        }
    }
    *reinterpret_cast<uint4*>(dst + c0) = *reinterpret_cast<uint4*>(v);
}

// ---------------- conv as one flattened GEMM: LDS-staged (global_load_lds w=16), double-buffered ----------------
// LDS XOR-swizzled (col16 ^= row&7; round 9: 6.08M conflict cycles -> 0).
// __launch_bounds__(256, 2): occupancy is LDS-capped at 2 blocks/CU (66 KB) anyway, so give
// the allocator the full 256-VGPR budget. Without the hint it targeted VGPR=88 against a
// ~100-reg live set (acc 64 + dbuf frags 32 + addr) -> suspected spill (WRITE 50.6 MB vs
// 26 MB logical in every round). Falsifier: if WRITE stays 50.6, the excess is 32B-store
// granularity, not spill.
__global__ __launch_bounds__(256, 2) void conv_mfma(const ushort* __restrict__ xpk,
                                                    const float* __restrict__ dmask,
                                                    const float* __restrict__ qmask,
                                                    const ushort* __restrict__ wp,
                                                    const float* __restrict__ b1,
                                                    const float* __restrict__ b2,
                                                    const float* __restrict__ b3,
                                                    ushort* __restrict__ dh,
                                                    ushort* __restrict__ dlo,
                                                    ushort* __restrict__ qh,
                                                    ushort* __restrict__ qlo) {
    __shared__ __align__(16) char smem[2][33024];

    const int tid = threadIdx.x;
    const int bid = blockIdx.x;
    // XCD-bijective swizzle: 792 = 8 * 99
    const int swz = (bid & 7) * (CONV_BLOCKS / 8) + (bid >> 3);
    const int z = swz % 3;
    const int tile = swz / 3;
    const int l0 = tile * 128;

    const int Kdim = EMBP * (z + 1);
    const int nk = 5 * (z + 1);                 // K-steps of 64
    const ushort* wpk = wp + WPOFF_C[z];
    const float* bias = (z == 0) ? b1 : ((z == 1) ? b2 : b3);

    const int wave = tid >> 6;
    const int lane = tid & 63;
    const int l15 = lane & 15;
    const int quad = lane >> 4;
    const int wm = wave >> 1;
    const int wn = wave & 1;

    const int srow = lane >> 3;
    // swizzled source column: col16' = (lane&7) ^ (lane>>3); row&7 of the LDS dest == lane>>3
    const int scolx = (((lane & 7) ^ (lane >> 3)) & 7) * 8;
    const ushort* a0 = xpk + (size_t)(l0 + wave * 8 + srow) * EMBP + scolx;
    const ushort* at = xpk + (size_t)(l0 + 128 + srow) * EMBP + scolx;  // tail rows 128..129
    const ushort* b0 = wpk + (size_t)(wave * 8 + srow) * Kdim + scolx;

    auto stage = [&](int buf, int kk) {
        int jj = (kk >= 10) ? 2 : ((kk >= 5) ? 1 : 0);
        int coff = (kk - jj * 5) * 64;
        int koff = kk * 64;
        char* abuf = smem[buf];
        char* bbuf = smem[buf] + 16640;
#pragma unroll
        for (int p = 0; p < 4; ++p)
            gl_lds16(a0 + p * (32 * EMBP) + coff, abuf + p * 4096 + wave * 1024);
        if (wave == 0 && lane < 16)
            gl_lds16(at + coff, abuf + 16384);
#pragma unroll
        for (int p = 0; p < 4; ++p)
            gl_lds16(b0 + (size_t)p * 32 * Kdim + koff, bbuf + p * 4096 + wave * 1024);
    };

    floatx4 acc[4][4];
#pragma unroll
    for (int i = 0; i < 4; ++i)
#pragma unroll
        for (int j = 0; j < 4; ++j) acc[i][j] = (floatx4)0.f;

    stage(0, 0);
    __syncthreads();

    int jjc = 0, ccc = 0;
    int buf = 0;
    for (int kk = 0; kk < nk; ++kk) {
        if (kk + 1 < nk) stage(buf ^ 1, kk + 1);
        const char* Ab = smem[buf];
        const char* Bb = smem[buf] + 16640;
        short8 af[2][4], bf[2][4];
#pragma unroll
        for (int h = 0; h < 2; ++h)
#pragma unroll
            for (int i = 0; i < 4; ++i) {
                int ra = wm * 64 + i * 16 + l15 + jjc;
                int rb = wn * 64 + i * 16 + l15;
                af[h][i] = *reinterpret_cast<const short8*>(
                    Ab + ra * 128 + ((((h << 2) | quad) ^ (ra & 7)) << 4));
                bf[h][i] = *reinterpret_cast<const short8*>(
                    Bb + rb * 128 + ((((h << 2) | quad) ^ (rb & 7)) << 4));
            }
#pragma unroll
        for (int h = 0; h < 2; ++h)
#pragma unroll
            for (int i = 0; i < 4; ++i)
#pragma unroll
                for (int j = 0; j < 4; ++j)
                    acc[i][j] = __builtin_amdgcn_mfma_f32_16x16x32_bf16(af[h][i], bf[h][j], acc[i][j], 0, 0, 0);
        ++ccc;
        if (ccc == 5) { ccc = 0; ++jjc; }
        __syncthreads();
        buf ^= 1;
    }

    // ---- epilogue: bias + relu + row L2-norm + mask; emit bf16 hi/lo planes ----
    float (*rowsum)[128] = reinterpret_cast<float(*)[128]>(smem);
    float bv[4];
#pragma unroll
    for (int j = 0; j < 4; ++j) bv[j] = bias[wn * 64 + j * 16 + l15];
#pragma unroll
    for (int i = 0; i < 4; ++i)
#pragma unroll
        for (int r = 0; r < 4; ++r) {
            float p = 0.f;
#pragma unroll
            for (int j = 0; j < 4; ++j) {
                float y = fmaxf(acc[i][j][r] + bv[j], 0.f);
                acc[i][j][r] = y;
                p += y * y;
            }
#pragma unroll
            for (int m = 1; m < 16; m <<= 1) p += __shfl_xor(p, m, 64);
            if (l15 == 0) rowsum[wn][wm * 64 + i * 16 + quad * 4 + r] = p;
        }
    __syncthreads();

#pragma unroll
    for (int i = 0; i < 4; ++i) {
#pragma unroll
        for (int rr = 0; rr < 4; ++rr) {
            int rl = wm * 64 + i * 16 + quad * 4 + rr;
            int r = l0 + rl;                    // global combined row
            float tot = rowsum[0][rl] + rowsum[1][rl];
            float mv;
            ushort* hp;
            ushort* lp;
            if (r < NB * DL) {
                int l = r & (DL - 1);
                if (l >= DL - z) continue;
                mv = dmask[r];
                size_t base = (size_t)z * DPLANE + (size_t)r * OD;
                hp = dh + base; lp = dlo + base;
            } else {
                int t = r - NB * DL;
                int l = t & (QL - 1);
                if (l >= QL - z) continue;
                mv = qmask[t];
                size_t base = (size_t)z * QPLANE + (size_t)t * OD;
                hp = qh + base; lp = qlo + base;
            }
            float sc = mv / (sqrtf(tot) + 1e-13f);
            int cb = wn * 64 + l15;
#pragma unroll
            for (int j = 0; j < 4; ++j) {
                float v = acc[i][j][rr] * sc;
                __hip_bfloat16 h = __float2bfloat16(v);
                float hf = __bfloat162float(h);
                hp[cb + j * 16] = *reinterpret_cast<ushort*>(&h);
                __hip_bfloat16 l = __float2bfloat16(v - hf);
                lp[cb + j * 16] = *reinterpret_cast<ushort*>(&l);
            }
        }
    }
}

// ---------------- matcher: round-9 structure, qi-fast pp decode, 6 blocks/CU ----------------
// grid: (vtile=8, b=32, pp=9), block 256 = 4 waves.
// __launch_bounds__(256, 6): measured profile is latency-mixed (VALU 45%, MFMA 5%, HBM 23%,
// nothing saturated) at Occupancy 35% under (256,4). LDS (19.9 KB) allows 8 blocks/CU and
// measured VGPR is 52; (256,6) -> 6 blocks/CU, VGPR budget 85 (safe margin above 52 --
// round 5 showed the allocator spills near tight budgets; WRITE/VGPR are the falsifier).
// Gaussian recurrence, 21 named-reg bins. Coalesced atomic commit.
__global__ __launch_bounds__(256, 6) void matcher_kernel(const ushort* __restrict__ qh_g,
                                                         const ushort* __restrict__ ql_g,
                                                         const ushort* __restrict__ vh_g,
                                                         const ushort* __restrict__ vl_g,
                                                         float* __restrict__ accb) {
    __shared__ __align__(16) float Sm[32 * 132];     // 16.9 KB S tile
    __shared__ float stageb[672];                    // 2.7 KB coalesced-commit staging

    const int tid = threadIdx.x;
    const int pp = blockIdx.z;
    const int b = blockIdx.y;
    const int v0 = blockIdx.x * 128;
    const int di = pp / 3;                // di SLOW
    const int qi = pp - di * 3;           // qi FAST: V-sharing blocks 256 apart
    const int Vk = 1024 - di;

    const ushort* qhb = qh_g + (size_t)qi * QPLANE + (size_t)b * (QL * OD);
    const ushort* qlb = ql_g + (size_t)qi * QPLANE + (size_t)b * (QL * OD);
    const ushort* vhb = vh_g + (size_t)di * DPLANE + (size_t)b * (DL * OD) + (size_t)v0 * OD;
    const ushort* vlb = vl_g + (size_t)di * DPLANE + (size_t)b * (DL * OD) + (size_t)v0 * OD;

    const int wave = tid >> 6;
    const int lane = tid & 63;
    const int l15 = lane & 15;
    const int quad = lane >> 4;

    floatx4 acc[2][2];
#pragma unroll
    for (int i = 0; i < 2; ++i)
#pragma unroll
        for (int j = 0; j < 2; ++j) acc[i][j] = (floatx4)0.f;

    // K = 128 as 4 windows of 32; lane's k-slice = quad*8 within each window.
#pragma unroll
    for (int kw = 0; kw < 4; ++kw) {
        const int ko = kw * 32 + quad * 8;
        short8 qh[2], ql[2], vh[2], vl[2];
#pragma unroll
        for (int i = 0; i < 2; ++i) {
            const int qr = i * 16 + l15;
            const int vr = wave * 32 + i * 16 + l15;
            qh[i] = *reinterpret_cast<const short8*>(qhb + qr * OD + ko);
            ql[i] = *reinterpret_cast<const short8*>(qlb + qr * OD + ko);
            vh[i] = *reinterpret_cast<const short8*>(vhb + (size_t)vr * OD + ko);
            vl[i] = *reinterpret_cast<const short8*>(vlb + (size_t)vr * OD + ko);
        }
#pragma unroll
        for (int i = 0; i < 2; ++i)
#pragma unroll
            for (int j = 0; j < 2; ++j) {
                acc[i][j] = __builtin_amdgcn_mfma_f32_16x16x32_bf16(qh[i], vh[j], acc[i][j], 0, 0, 0);
                acc[i][j] = __builtin_amdgcn_mfma_f32_16x16x32_bf16(qh[i], vl[j], acc[i][j], 0, 0, 0);
                acc[i][j] = __builtin_amdgcn_mfma_f32_16x16x32_bf16(ql[i], vh[j], acc[i][j], 0, 0, 0);
            }
    }

    // ---- S tile to LDS (stride 132 f32), poison v >= vmax with 1e4 ----
    const int vmax = min(128, Vk - v0);
#pragma unroll
    for (int i = 0; i < 2; ++i)
#pragma unroll
        for (int j = 0; j < 2; ++j)
#pragma unroll
            for (int r = 0; r < 4; ++r) {
                int q = i * 16 + quad * 4 + r;
                int v = wave * 32 + j * 16 + l15;
                float val = acc[i][j][r];
                if (v >= vmax) val = 1.0e4f;
                Sm[q * 132 + v] = val;
            }
    __syncthreads();

    // ---- gaussian phase: thread = (q = tid>>3, chunk c = tid&7 -> v in [c*16, c*16+16)) ----
    {
        const int q = tid >> 3;
        const int c = tid & 7;
        const float* srow = &Sm[q * 132 + c * 16];
        const float Am  = -72.13475204f;     // -log2e/(2*0.1^2)
        const float Am5 = -14.426950408f;    // 0.2*Am
        const float A0  = -721347.52f;       // -log2e/(2*0.001^2)
        const float C   = 0x1.0p-126f;

        float s00 = 0.f, s01 = 0.f, s02 = 0.f, s03 = 0.f, s04 = 0.f, s05 = 0.f,
              s06 = 0.f, s07 = 0.f, s08 = 0.f, s09 = 0.f, s10 = 0.f, s11 = 0.f,
              s12 = 0.f, s13 = 0.f, s14 = 0.f, s15 = 0.f, s16 = 0.f, s17 = 0.f,
              s18 = 0.f, s19 = 0.f, s20 = 0.f;

#define GACC(B) { B = __builtin_fmaf(tx, C, B); B = __builtin_fmaf(ty, C, B); \
                  B = __builtin_fmaf(tz, C, B); B = __builtin_fmaf(tw, C, B); }
#define GSTEP(B, g) { tx *= Rx * (g); ty *= Ry * (g); tz *= Rz * (g); tw *= Rw * (g); GACC(B) }

#pragma unroll
        for (int jj = 0; jj < 4; ++jj) {
            float4 s4 = *reinterpret_cast<const float4*>(srow + jj * 4);
            float dx = s4.x - 0.95f, dy = s4.y - 0.95f, dz = s4.z - 0.95f, dwv = s4.w - 0.95f;
            float tx = __builtin_exp2f(__builtin_fmaf(Am * dx, dx, 126.f));  // 2^126 * term_1
            float ty = __builtin_exp2f(__builtin_fmaf(Am * dy, dy, 126.f));
            float tz = __builtin_exp2f(__builtin_fmaf(Am * dz, dz, 126.f));
            float tw = __builtin_exp2f(__builtin_fmaf(Am * dwv, dwv, 126.f));
            float Rx = __builtin_exp2f(Am5 * dx);
            float Ry = __builtin_exp2f(Am5 * dy);
            float Rz = __builtin_exp2f(Am5 * dz);
            float Rw = __builtin_exp2f(Am5 * dwv);
            GACC(s01)
            GSTEP(s02, 6.0653066e-01f) GSTEP(s03, 2.2313016e-01f)
            GSTEP(s04, 8.2084999e-02f) GSTEP(s05, 3.0197383e-02f)
            GSTEP(s06, 1.1108997e-02f) GSTEP(s07, 4.0867714e-03f)
            GSTEP(s08, 1.5034391e-03f) GSTEP(s09, 5.5308438e-04f)
            GSTEP(s10, 2.0346837e-04f) GSTEP(s11, 7.4851830e-05f)
            GSTEP(s12, 2.7536450e-05f) GSTEP(s13, 1.0130095e-05f)
            GSTEP(s14, 3.7266532e-06f) GSTEP(s15, 1.3709590e-06f)
            GSTEP(s16, 5.0434766e-07f) GSTEP(s17, 1.8553914e-07f)
            GSTEP(s18, 6.8256033e-08f) GSTEP(s19, 2.5110699e-08f)
            GSTEP(s20, 9.2374496e-09f)
            float ex = s4.x - 1.f, ey = s4.y - 1.f, ez = s4.z - 1.f, ew = s4.w - 1.f;
            s00 += __builtin_exp2f((A0 * ex) * ex);
            s00 += __builtin_exp2f((A0 * ey) * ey);
            s00 += __builtin_exp2f((A0 * ez) * ez);
            s00 += __builtin_exp2f((A0 * ew) * ew);
        }
#undef GSTEP
#undef GACC

        // reduce over the 8 v-chunks (lane bits 0..2); c==0 stages to LDS
#define GRED(B) { B += __shfl_xor(B, 1, 64); B += __shfl_xor(B, 2, 64); B += __shfl_xor(B, 4, 64); }
        GRED(s00) GRED(s01) GRED(s02) GRED(s03) GRED(s04) GRED(s05) GRED(s06)
        GRED(s07) GRED(s08) GRED(s09) GRED(s10) GRED(s11) GRED(s12) GRED(s13)
        GRED(s14) GRED(s15) GRED(s16) GRED(s17) GRED(s18) GRED(s19) GRED(s20)
#undef GRED
        if (c == 0) {
            float* sp = &stageb[q * KNUM];
            sp[0]  = s00; sp[1]  = s01; sp[2]  = s02; sp[3]  = s03; sp[4]  = s04;
            sp[5]  = s05; sp[6]  = s06; sp[7]  = s07; sp[8]  = s08; sp[9]  = s09;
            sp[10] = s10; sp[11] = s11; sp[12] = s12; sp[13] = s13; sp[14] = s14;
            sp[15] = s15; sp[16] = s16; sp[17] = s17; sp[18] = s18; sp[19] = s19;
            sp[20] = s20;
        }
    }
    __syncthreads();

    // ---- coalesced atomic commit: 672 contiguous floats; logical pair id = qi*3+di ----
    {
        float* dst = &accb[((size_t)((qi * 3 + di) * NB + b) * QL) * KNUM];
        for (int i = tid; i < 32 * KNUM; i += 256)
            atomicAdd(dst + i, stageb[i]);
    }
}

// ---------------- finalize ----------------
__global__ void finalize_kernel(const float* __restrict__ accb,
                                const float* __restrict__ qmask,
                                const float* __restrict__ dw,
                                const float* __restrict__ db,
                                float* __restrict__ out) {
    __shared__ float prod[192];
    int b = blockIdx.x;
    int tid = threadIdx.x;
    if (tid < 189) {
        int pq = tid / 21;
        int t = tid - pq * 21;
        int qi = pq / 3;
        int Qk = 32 - qi;
        const float* ab = accb + ((pq * NB + b) * QL) * KNUM + t;
        float s = 0.f;
        for (int q = 0; q < Qk; ++q)
            s += logf(fmaxf(ab[q * KNUM], 1e-10f)) * qmask[b * QL + q];
        float lg = s * 0.01f;
        out[NB + b * 189 + tid] = lg;
        prod[tid] = lg * dw[tid];
    }
    __syncthreads();
    if (tid == 0) {
        float sc = db[0];
        for (int i = 0; i < 189; ++i) sc += prod[i];
        out[b] = sc;
    }
}

// ---------------- launcher ----------------
extern "C" void kernel_launch(void* const* d_in, const int* in_sizes, int n_in,
                              void* d_out, int out_size, void* d_ws, size_t ws_size,
                              hipStream_t stream) {
    const int* qids = (const int*)d_in[0];
    const float* qmask = (const float*)d_in[1];
    const int* dids = (const int*)d_in[2];
    const float* dmask = (const float*)d_in[3];
    const float* emb = (const float*)d_in[4];
    const float* w1 = (const float*)d_in[5];
    const float* b1 = (const float*)d_in[6];
    const float* w2 = (const float*)d_in[7];
    const float* b2 = (const float*)d_in[8];
    const float* w3 = (const float*)d_in[9];
    const float* b3 = (const float*)d_in[10];
    const float* dw = (const float*)d_in[11];
    const float* db = (const float*)d_in[12];
    float* out = (float*)d_out;
    float* ws = (float*)d_ws;

    ushort* wp  = (ushort*)(ws + WP_OFF);
    ushort* dpk = (ushort*)(ws + DPK_OFF);
    ushort* qpk = (ushort*)(ws + QPK_OFF);
    ushort* qh  = (ushort*)(ws + QH_OFF);
    ushort* qlo = (ushort*)(ws + QLO_OFF);
    ushort* dh  = (ushort*)(ws + DH_OFF);
    ushort* dlo = (ushort*)(ws + DLO_OFF);
    float* accb = ws + ACC_OFF;

    hipMemsetAsync(accb, 0, ACC_SZ * sizeof(float), stream);
    gather_prep<<<(PREPW_N + GATHER_N + 255) / 256, 256, 0, stream>>>(
        emb, dids, qids, w1, w2, w3, dpk, qpk, wp);

    conv_mfma<<<CONV_BLOCKS, 256, 0, stream>>>(dpk, dmask, qmask, wp, b1, b2, b3, dh, dlo, qh, qlo);

    matcher_kernel<<<dim3(8, NB, 9), 256, 0, stream>>>(qh, qlo, dh, dlo, accb);
    finalize_kernel<<<NB, 256, 0, stream>>>(accb, qmask, dw, db, out);
}

// Round 15
// 219.491 us; speedup vs baseline: 1.0982x; 1.0982x over previous
//
#include <hip/hip_runtime.h>
#include <hip/hip_bf16.h>
#include <math.h>

// ---------------- problem constants ----------------
#define NB 32
#define QL 32
#define DL 1024
#define EMB 300
#define EMBP 320            // padded K-dim per tap (zeros 300..319)
#define OD 128
#define KNUM 21
#define VOCAB 50000

typedef short short8 __attribute__((ext_vector_type(8)));
typedef float floatx4 __attribute__((ext_vector_type(4)));

// workspace layout (in float units)
static const size_t WP_OFF  = 0;           // packed bf16 weights: 245760 ushorts = 122880 fl
static const size_t DPK_OFF = 122880;      // packed doc bf16 [32*1024][320] = 5242880 fl
static const size_t QPK_OFF = 5365760;     // packed query bf16 [(1024+2)][320] = 164160 fl
// encoder outputs stored as SPLIT bf16 hi/lo planes
static const size_t QH_OFF  = 5529920;     // qenc hi: 3 * 32*32*128 us = 196608 fl
static const size_t QLO_OFF = 5726528;     // qenc lo
static const size_t DH_OFF  = 5923136;     // denc hi: 3 * 32*1024*128 us = 6291456 fl
static const size_t DLO_OFF = 12214592;    // denc lo
static const size_t ACC_OFF = 18506048;
static const int ACC_SZ = 9 * NB * QL * KNUM;          // 193536

#define QPLANE 131072      // ushorts per z-plane of qenc (32*32*128)
#define DPLANE 4194304     // ushorts per z-plane of denc (32*1024*128)

// combined packed rows: doc (32768) + query (1024) + 2 zero guard rows
#define MROWS (NB * DL + NB * QL)      // 33792 = 264 * 128 exactly
#define MTILES 264
#define CONV_BLOCKS (MTILES * 3)       // 792, divisible by 8 (XCD swizzle bijective)

#define PREPW_N 245760
#define GATHER_N ((MROWS + 2) * 40)

__device__ __constant__ int WPOFF_C[3] = {0, 40960, 122880};

__device__ __forceinline__ void gl_lds16(const ushort* g, char* l) {
    __builtin_amdgcn_global_load_lds(
        (const __attribute__((address_space(1))) unsigned int*)(g),
        (__attribute__((address_space(3))) unsigned int*)(l), 16, 0, 0);
}

__device__ __forceinline__ ushort bf16_bits(float f) {
    __hip_bfloat16 h = __float2bfloat16(f);
    return *reinterpret_cast<ushort*>(&h);
}

// ---------------- fused producer: weights->bf16 pack + token-row gather/pack ----------------
__global__ void gather_prep(const float* __restrict__ emb,
                            const int* __restrict__ dids, const int* __restrict__ qids,
                            const float* __restrict__ w1, const float* __restrict__ w2,
                            const float* __restrict__ w3,
                            ushort* __restrict__ dpk, ushort* __restrict__ qpk,
                            ushort* __restrict__ wp) {
    int idx = blockIdx.x * 256 + threadIdx.x;
    if (idx < PREPW_N) {
        // ---- weights -> bf16, layout [o][j*320+c] ----
        const float* src;
        int k, rel, base;
        if (idx < 40960)        { k = 1; rel = idx;          src = w1; base = 0; }
        else if (idx < 122880)  { k = 2; rel = idx - 40960;  src = w2; base = 40960; }
        else                    { k = 3; rel = idx - 122880; src = w3; base = 122880; }
        int kd = 320 * k;
        int o = rel / kd;
        int jc = rel - o * kd;
        int j = jc / EMBP;
        int c = jc - j * EMBP;
        float f = (c < EMB) ? src[(o * EMB + c) * k + j] : 0.f;
        wp[base + rel] = bf16_bits(f);
        return;
    }
    idx -= PREPW_N;
    if (idx >= GATHER_N) return;
    // ---- gather token rows: fp32 emb -> packed bf16 [row][320] (doc + query + 2 zero rows) ----
    const int DROWS = NB * DL;
    int r = idx / 40;
    int c0 = (idx - r * 40) * 8;
    int rid;
    ushort* dst;
    if (r < DROWS) { rid = dids[r]; dst = dpk + (size_t)r * EMBP; }
    else if (r < DROWS + NB * QL) { rid = qids[r - DROWS]; dst = qpk + (size_t)(r - DROWS) * EMBP; }
    else {
        uint4 zz = {0u, 0u, 0u, 0u};
        *reinterpret_cast<uint4*>(qpk + (size_t)(r - DROWS) * EMBP + c0) = zz;
        return;
    }
    const float* erow = emb + (size_t)rid * EMB;
    ushort v[8];
    if (c0 + 8 <= EMB) {
        float4 f0 = *reinterpret_cast<const float4*>(erow + c0);
        float4 f1 = *reinterpret_cast<const float4*>(erow + c0 + 4);
        float fv[8] = {f0.x, f0.y, f0.z, f0.w, f1.x, f1.y, f1.z, f1.w};
#pragma unroll
        for (int i = 0; i < 8; ++i) v[i] = bf16_bits(fv[i]);
    } else {
#pragma unroll
        for (int i = 0; i < 8; ++i) {
            int c = c0 + i;
            v[i] = bf16_bits((c < EMB) ? erow[c] : 0.f);
        }
    }
    *reinterpret_cast<uint4*>(dst + c0) = *reinterpret_cast<uint4*>(v);
}

// ---------------- conv as one flattened GEMM: LDS-staged (global_load_lds w=16), double-buffered ----------------
// LDS XOR-swizzled (col16 ^= row&7; round 9: 6.08M conflict cycles -> 0).
// __launch_bounds__(256, 2): occupancy is LDS-capped at 2 blocks/CU (66 KB) anyway; give
// the allocator the full VGPR budget (no-hint targeted VGPR=88 against a ~100-reg live set).
__global__ __launch_bounds__(256, 2) void conv_mfma(const ushort* __restrict__ xpk,
                                                    const float* __restrict__ dmask,
                                                    const float* __restrict__ qmask,
                                                    const ushort* __restrict__ wp,
                                                    const float* __restrict__ b1,
                                                    const float* __restrict__ b2,
                                                    const float* __restrict__ b3,
                                                    ushort* __restrict__ dh,
                                                    ushort* __restrict__ dlo,
                                                    ushort* __restrict__ qh,
                                                    ushort* __restrict__ qlo) {
    __shared__ __align__(16) char smem[2][33024];

    const int tid = threadIdx.x;
    const int bid = blockIdx.x;
    // XCD-bijective swizzle: 792 = 8 * 99
    const int swz = (bid & 7) * (CONV_BLOCKS / 8) + (bid >> 3);
    const int z = swz % 3;
    const int tile = swz / 3;
    const int l0 = tile * 128;

    const int Kdim = EMBP * (z + 1);
    const int nk = 5 * (z + 1);                 // K-steps of 64
    const ushort* wpk = wp + WPOFF_C[z];
    const float* bias = (z == 0) ? b1 : ((z == 1) ? b2 : b3);

    const int wave = tid >> 6;
    const int lane = tid & 63;
    const int l15 = lane & 15;
    const int quad = lane >> 4;
    const int wm = wave >> 1;
    const int wn = wave & 1;

    const int srow = lane >> 3;
    // swizzled source column: col16' = (lane&7) ^ (lane>>3); row&7 of the LDS dest == lane>>3
    const int scolx = (((lane & 7) ^ (lane >> 3)) & 7) * 8;
    const ushort* a0 = xpk + (size_t)(l0 + wave * 8 + srow) * EMBP + scolx;
    const ushort* at = xpk + (size_t)(l0 + 128 + srow) * EMBP + scolx;  // tail rows 128..129
    const ushort* b0 = wpk + (size_t)(wave * 8 + srow) * Kdim + scolx;

    auto stage = [&](int buf, int kk) {
        int jj = (kk >= 10) ? 2 : ((kk >= 5) ? 1 : 0);
        int coff = (kk - jj * 5) * 64;
        int koff = kk * 64;
        char* abuf = smem[buf];
        char* bbuf = smem[buf] + 16640;
#pragma unroll
        for (int p = 0; p < 4; ++p)
            gl_lds16(a0 + p * (32 * EMBP) + coff, abuf + p * 4096 + wave * 1024);
        if (wave == 0 && lane < 16)
            gl_lds16(at + coff, abuf + 16384);
#pragma unroll
        for (int p = 0; p < 4; ++p)
            gl_lds16(b0 + (size_t)p * 32 * Kdim + koff, bbuf + p * 4096 + wave * 1024);
    };

    floatx4 acc[4][4];
#pragma unroll
    for (int i = 0; i < 4; ++i)
#pragma unroll
        for (int j = 0; j < 4; ++j) acc[i][j] = (floatx4)0.f;

    stage(0, 0);
    __syncthreads();

    int jjc = 0, ccc = 0;
    int buf = 0;
    for (int kk = 0; kk < nk; ++kk) {
        if (kk + 1 < nk) stage(buf ^ 1, kk + 1);
        const char* Ab = smem[buf];
        const char* Bb = smem[buf] + 16640;
        short8 af[2][4], bf[2][4];
#pragma unroll
        for (int h = 0; h < 2; ++h)
#pragma unroll
            for (int i = 0; i < 4; ++i) {
                int ra = wm * 64 + i * 16 + l15 + jjc;
                int rb = wn * 64 + i * 16 + l15;
                af[h][i] = *reinterpret_cast<const short8*>(
                    Ab + ra * 128 + ((((h << 2) | quad) ^ (ra & 7)) << 4));
                bf[h][i] = *reinterpret_cast<const short8*>(
                    Bb + rb * 128 + ((((h << 2) | quad) ^ (rb & 7)) << 4));
            }
#pragma unroll
        for (int h = 0; h < 2; ++h)
#pragma unroll
            for (int i = 0; i < 4; ++i)
#pragma unroll
                for (int j = 0; j < 4; ++j)
                    acc[i][j] = __builtin_amdgcn_mfma_f32_16x16x32_bf16(af[h][i], bf[h][j], acc[i][j], 0, 0, 0);
        ++ccc;
        if (ccc == 5) { ccc = 0; ++jjc; }
        __syncthreads();
        buf ^= 1;
    }

    // ---- epilogue: bias + relu + row L2-norm + mask; emit bf16 hi/lo planes ----
    float (*rowsum)[128] = reinterpret_cast<float(*)[128]>(smem);
    float bv[4];
#pragma unroll
    for (int j = 0; j < 4; ++j) bv[j] = bias[wn * 64 + j * 16 + l15];
#pragma unroll
    for (int i = 0; i < 4; ++i)
#pragma unroll
        for (int r = 0; r < 4; ++r) {
            float p = 0.f;
#pragma unroll
            for (int j = 0; j < 4; ++j) {
                float y = fmaxf(acc[i][j][r] + bv[j], 0.f);
                acc[i][j][r] = y;
                p += y * y;
            }
#pragma unroll
            for (int m = 1; m < 16; m <<= 1) p += __shfl_xor(p, m, 64);
            if (l15 == 0) rowsum[wn][wm * 64 + i * 16 + quad * 4 + r] = p;
        }
    __syncthreads();

#pragma unroll
    for (int i = 0; i < 4; ++i) {
#pragma unroll
        for (int rr = 0; rr < 4; ++rr) {
            int rl = wm * 64 + i * 16 + quad * 4 + rr;
            int r = l0 + rl;                    // global combined row
            float tot = rowsum[0][rl] + rowsum[1][rl];
            float mv;
            ushort* hp;
            ushort* lp;
            if (r < NB * DL) {
                int l = r & (DL - 1);
                if (l >= DL - z) continue;
                mv = dmask[r];
                size_t base = (size_t)z * DPLANE + (size_t)r * OD;
                hp = dh + base; lp = dlo + base;
            } else {
                int t = r - NB * DL;
                int l = t & (QL - 1);
                if (l >= QL - z) continue;
                mv = qmask[t];
                size_t base = (size_t)z * QPLANE + (size_t)t * OD;
                hp = qh + base; lp = qlo + base;
            }
            float sc = mv / (sqrtf(tot) + 1e-13f);
            int cb = wn * 64 + l15;
#pragma unroll
            for (int j = 0; j < 4; ++j) {
                float v = acc[i][j][rr] * sc;
                __hip_bfloat16 h = __float2bfloat16(v);
                float hf = __bfloat162float(h);
                hp[cb + j * 16] = *reinterpret_cast<ushort*>(&h);
                __hip_bfloat16 l = __float2bfloat16(v - hf);
                lp[cb + j * 16] = *reinterpret_cast<ushort*>(&l);
            }
        }
    }
}

// ---------------- matcher: round-9 structure, qi-fast pp decode, __launch_bounds__(256,4) ----------------
// grid: (vtile=8, b=32, pp=9), block 256 = 4 waves.
// (256,4) is the UNIQUE good allocator point for this kernel, confirmed from both sides:
// no hint -> targets VGPR=36, spills the 21 bins (rounds 4/5: 130us); (256,6) -> VGPR=40,
// spills again (round 14: WRITE 75MB, 94.8us); (256,4) -> VGPR=52, WRITE=6MB, 50.5us.
// qi-fast pp decode (di=pp/3, qi=pp%3): V-sharing blocks 256 apart in dispatch order
// (neutral-to-positive, round 13). Gaussian recurrence, 21 named-reg bins. Coalesced commit.
__global__ __launch_bounds__(256, 4) void matcher_kernel(const ushort* __restrict__ qh_g,
                                                         const ushort* __restrict__ ql_g,
                                                         const ushort* __restrict__ vh_g,
                                                         const ushort* __restrict__ vl_g,
                                                         float* __restrict__ accb) {
    __shared__ __align__(16) float Sm[32 * 132];     // 16.9 KB S tile
    __shared__ float stageb[672];                    // 2.7 KB coalesced-commit staging

    const int tid = threadIdx.x;
    const int pp = blockIdx.z;
    const int b = blockIdx.y;
    const int v0 = blockIdx.x * 128;
    const int di = pp / 3;                // di SLOW
    const int qi = pp - di * 3;           // qi FAST: V-sharing blocks 256 apart
    const int Vk = 1024 - di;

    const ushort* qhb = qh_g + (size_t)qi * QPLANE + (size_t)b * (QL * OD);
    const ushort* qlb = ql_g + (size_t)qi * QPLANE + (size_t)b * (QL * OD);
    const ushort* vhb = vh_g + (size_t)di * DPLANE + (size_t)b * (DL * OD) + (size_t)v0 * OD;
    const ushort* vlb = vl_g + (size_t)di * DPLANE + (size_t)b * (DL * OD) + (size_t)v0 * OD;

    const int wave = tid >> 6;
    const int lane = tid & 63;
    const int l15 = lane & 15;
    const int quad = lane >> 4;

    floatx4 acc[2][2];
#pragma unroll
    for (int i = 0; i < 2; ++i)
#pragma unroll
        for (int j = 0; j < 2; ++j) acc[i][j] = (floatx4)0.f;

    // K = 128 as 4 windows of 32; lane's k-slice = quad*8 within each window.
#pragma unroll
    for (int kw = 0; kw < 4; ++kw) {
        const int ko = kw * 32 + quad * 8;
        short8 qh[2], ql[2], vh[2], vl[2];
#pragma unroll
        for (int i = 0; i < 2; ++i) {
            const int qr = i * 16 + l15;
            const int vr = wave * 32 + i * 16 + l15;
            qh[i] = *reinterpret_cast<const short8*>(qhb + qr * OD + ko);
            ql[i] = *reinterpret_cast<const short8*>(qlb + qr * OD + ko);
            vh[i] = *reinterpret_cast<const short8*>(vhb + (size_t)vr * OD + ko);
            vl[i] = *reinterpret_cast<const short8*>(vlb + (size_t)vr * OD + ko);
        }
#pragma unroll
        for (int i = 0; i < 2; ++i)
#pragma unroll
            for (int j = 0; j < 2; ++j) {
                acc[i][j] = __builtin_amdgcn_mfma_f32_16x16x32_bf16(qh[i], vh[j], acc[i][j], 0, 0, 0);
                acc[i][j] = __builtin_amdgcn_mfma_f32_16x16x32_bf16(qh[i], vl[j], acc[i][j], 0, 0, 0);
                acc[i][j] = __builtin_amdgcn_mfma_f32_16x16x32_bf16(ql[i], vh[j], acc[i][j], 0, 0, 0);
            }
    }

    // ---- S tile to LDS (stride 132 f32), poison v >= vmax with 1e4 ----
    const int vmax = min(128, Vk - v0);
#pragma unroll
    for (int i = 0; i < 2; ++i)
#pragma unroll
        for (int j = 0; j < 2; ++j)
#pragma unroll
            for (int r = 0; r < 4; ++r) {
                int q = i * 16 + quad * 4 + r;
                int v = wave * 32 + j * 16 + l15;
                float val = acc[i][j][r];
                if (v >= vmax) val = 1.0e4f;
                Sm[q * 132 + v] = val;
            }
    __syncthreads();

    // ---- gaussian phase: thread = (q = tid>>3, chunk c = tid&7 -> v in [c*16, c*16+16)) ----
    {
        const int q = tid >> 3;
        const int c = tid & 7;
        const float* srow = &Sm[q * 132 + c * 16];
        const float Am  = -72.13475204f;     // -log2e/(2*0.1^2)
        const float Am5 = -14.426950408f;    // 0.2*Am
        const float A0  = -721347.52f;       // -log2e/(2*0.001^2)
        const float C   = 0x1.0p-126f;

        float s00 = 0.f, s01 = 0.f, s02 = 0.f, s03 = 0.f, s04 = 0.f, s05 = 0.f,
              s06 = 0.f, s07 = 0.f, s08 = 0.f, s09 = 0.f, s10 = 0.f, s11 = 0.f,
              s12 = 0.f, s13 = 0.f, s14 = 0.f, s15 = 0.f, s16 = 0.f, s17 = 0.f,
              s18 = 0.f, s19 = 0.f, s20 = 0.f;

#define GACC(B) { B = __builtin_fmaf(tx, C, B); B = __builtin_fmaf(ty, C, B); \
                  B = __builtin_fmaf(tz, C, B); B = __builtin_fmaf(tw, C, B); }
#define GSTEP(B, g) { tx *= Rx * (g); ty *= Ry * (g); tz *= Rz * (g); tw *= Rw * (g); GACC(B) }

#pragma unroll
        for (int jj = 0; jj < 4; ++jj) {
            float4 s4 = *reinterpret_cast<const float4*>(srow + jj * 4);
            float dx = s4.x - 0.95f, dy = s4.y - 0.95f, dz = s4.z - 0.95f, dwv = s4.w - 0.95f;
            float tx = __builtin_exp2f(__builtin_fmaf(Am * dx, dx, 126.f));  // 2^126 * term_1
            float ty = __builtin_exp2f(__builtin_fmaf(Am * dy, dy, 126.f));
            float tz = __builtin_exp2f(__builtin_fmaf(Am * dz, dz, 126.f));
            float tw = __builtin_exp2f(__builtin_fmaf(Am * dwv, dwv, 126.f));
            float Rx = __builtin_exp2f(Am5 * dx);
            float Ry = __builtin_exp2f(Am5 * dy);
            float Rz = __builtin_exp2f(Am5 * dz);
            float Rw = __builtin_exp2f(Am5 * dwv);
            GACC(s01)
            GSTEP(s02, 6.0653066e-01f) GSTEP(s03, 2.2313016e-01f)
            GSTEP(s04, 8.2084999e-02f) GSTEP(s05, 3.0197383e-02f)
            GSTEP(s06, 1.1108997e-02f) GSTEP(s07, 4.0867714e-03f)
            GSTEP(s08, 1.5034391e-03f) GSTEP(s09, 5.5308438e-04f)
            GSTEP(s10, 2.0346837e-04f) GSTEP(s11, 7.4851830e-05f)
            GSTEP(s12, 2.7536450e-05f) GSTEP(s13, 1.0130095e-05f)
            GSTEP(s14, 3.7266532e-06f) GSTEP(s15, 1.3709590e-06f)
            GSTEP(s16, 5.0434766e-07f) GSTEP(s17, 1.8553914e-07f)
            GSTEP(s18, 6.8256033e-08f) GSTEP(s19, 2.5110699e-08f)
            GSTEP(s20, 9.2374496e-09f)
            float ex = s4.x - 1.f, ey = s4.y - 1.f, ez = s4.z - 1.f, ew = s4.w - 1.f;
            s00 += __builtin_exp2f((A0 * ex) * ex);
            s00 += __builtin_exp2f((A0 * ey) * ey);
            s00 += __builtin_exp2f((A0 * ez) * ez);
            s00 += __builtin_exp2f((A0 * ew) * ew);
        }
#undef GSTEP
#undef GACC

        // reduce over the 8 v-chunks (lane bits 0..2); c==0 stages to LDS
#define GRED(B) { B += __shfl_xor(B, 1, 64); B += __shfl_xor(B, 2, 64); B += __shfl_xor(B, 4, 64); }
        GRED(s00) GRED(s01) GRED(s02) GRED(s03) GRED(s04) GRED(s05) GRED(s06)
        GRED(s07) GRED(s08) GRED(s09) GRED(s10) GRED(s11) GRED(s12) GRED(s13)
        GRED(s14) GRED(s15) GRED(s16) GRED(s17) GRED(s18) GRED(s19) GRED(s20)
#undef GRED
        if (c == 0) {
            float* sp = &stageb[q * KNUM];
            sp[0]  = s00; sp[1]  = s01; sp[2]  = s02; sp[3]  = s03; sp[4]  = s04;
            sp[5]  = s05; sp[6]  = s06; sp[7]  = s07; sp[8]  = s08; sp[9]  = s09;
            sp[10] = s10; sp[11] = s11; sp[12] = s12; sp[13] = s13; sp[14] = s14;
            sp[15] = s15; sp[16] = s16; sp[17] = s17; sp[18] = s18; sp[19] = s19;
            sp[20] = s20;
        }
    }
    __syncthreads();

    // ---- coalesced atomic commit: 672 contiguous floats; logical pair id = qi*3+di ----
    {
        float* dst = &accb[((size_t)((qi * 3 + di) * NB + b) * QL) * KNUM];
        for (int i = tid; i < 32 * KNUM; i += 256)
            atomicAdd(dst + i, stageb[i]);
    }
}

// ---------------- finalize ----------------
__global__ void finalize_kernel(const float* __restrict__ accb,
                                const float* __restrict__ qmask,
                                const float* __restrict__ dw,
                                const float* __restrict__ db,
                                float* __restrict__ out) {
    __shared__ float prod[192];
    int b = blockIdx.x;
    int tid = threadIdx.x;
    if (tid < 189) {
        int pq = tid / 21;
        int t = tid - pq * 21;
        int qi = pq / 3;
        int Qk = 32 - qi;
        const float* ab = accb + ((pq * NB + b) * QL) * KNUM + t;
        float s = 0.f;
        for (int q = 0; q < Qk; ++q)
            s += logf(fmaxf(ab[q * KNUM], 1e-10f)) * qmask[b * QL + q];
        float lg = s * 0.01f;
        out[NB + b * 189 + tid] = lg;
        prod[tid] = lg * dw[tid];
    }
    __syncthreads();
    if (tid == 0) {
        float sc = db[0];
        for (int i = 0; i < 189; ++i) sc += prod[i];
        out[b] = sc;
    }
}

// ---------------- launcher ----------------
extern "C" void kernel_launch(void* const* d_in, const int* in_sizes, int n_in,
                              void* d_out, int out_size, void* d_ws, size_t ws_size,
                              hipStream_t stream) {
    const int* qids = (const int*)d_in[0];
    const float* qmask = (const float*)d_in[1];
    const int* dids = (const int*)d_in[2];
    const float* dmask = (const float*)d_in[3];
    const float* emb = (const float*)d_in[4];
    const float* w1 = (const float*)d_in[5];
    const float* b1 = (const float*)d_in[6];
    const float* w2 = (const float*)d_in[7];
    const float* b2 = (const float*)d_in[8];
    const float* w3 = (const float*)d_in[9];
    const float* b3 = (const float*)d_in[10];
    const float* dw = (const float*)d_in[11];
    const float* db = (const float*)d_in[12];
    float* out = (float*)d_out;
    float* ws = (float*)d_ws;

    ushort* wp  = (ushort*)(ws + WP_OFF);
    ushort* dpk = (ushort*)(ws + DPK_OFF);
    ushort* qpk = (ushort*)(ws + QPK_OFF);
    ushort* qh  = (ushort*)(ws + QH_OFF);
    ushort* qlo = (ushort*)(ws + QLO_OFF);
    ushort* dh  = (ushort*)(ws + DH_OFF);
    ushort* dlo = (ushort*)(ws + DLO_OFF);
    float* accb = ws + ACC_OFF;

    hipMemsetAsync(accb, 0, ACC_SZ * sizeof(float), stream);
    gather_prep<<<(PREPW_N + GATHER_N + 255) / 256, 256, 0, stream>>>(
        emb, dids, qids, w1, w2, w3, dpk, qpk, wp);

    conv_mfma<<<CONV_BLOCKS, 256, 0, stream>>>(dpk, dmask, qmask, wp, b1, b2, b3, dh, dlo, qh, qlo);

    matcher_kernel<<<dim3(8, NB, 9), 256, 0, stream>>>(qh, qlo, dh, dlo, accb);
    finalize_kernel<<<NB, 256, 0, stream>>>(accb, qmask, dw, db, out);
}

// Round 16
// 217.735 us; speedup vs baseline: 1.1071x; 1.0081x over previous
//
#include <hip/hip_runtime.h>
#include <hip/hip_bf16.h>
#include <math.h>

// ---------------- problem constants ----------------
#define NB 32
#define QL 32
#define DL 1024
#define EMB 300
#define EMBP 320            // padded K-dim per tap (zeros 300..319)
#define OD 128
#define KNUM 21
#define VOCAB 50000

typedef short short8 __attribute__((ext_vector_type(8)));
typedef float floatx4 __attribute__((ext_vector_type(4)));

// workspace layout (in float units)
static const size_t WP_OFF  = 0;           // packed bf16 weights: 245760 ushorts = 122880 fl
static const size_t DPK_OFF = 122880;      // packed doc bf16 [32*1024][320] = 5242880 fl
static const size_t QPK_OFF = 5365760;     // packed query bf16 [(1024+2)][320] = 164160 fl
// encoder outputs stored as SPLIT bf16 hi/lo planes
static const size_t QH_OFF  = 5529920;     // qenc hi: 3 * 32*32*128 us = 196608 fl
static const size_t QLO_OFF = 5726528;     // qenc lo
static const size_t DH_OFF  = 5923136;     // denc hi: 3 * 32*1024*128 us = 6291456 fl
static const size_t DLO_OFF = 12214592;    // denc lo
static const size_t ACC_OFF = 18506048;
static const int ACC_SZ = 9 * NB * QL * KNUM;          // 193536

#define QPLANE 131072      // ushorts per z-plane of qenc (32*32*128)
#define DPLANE 4194304     // ushorts per z-plane of denc (32*1024*128)

// combined packed rows: doc (32768) + query (1024) + 2 zero guard rows
#define MROWS (NB * DL + NB * QL)      // 33792 = 264 * 128 exactly
#define MTILES 264
#define CONV_BLOCKS (MTILES * 3)       // 792, divisible by 8 (XCD swizzle bijective)

#define PREPW_N 245760
#define GATHER_N ((MROWS + 2) * 40)

__device__ __constant__ int WPOFF_C[3] = {0, 40960, 122880};

__device__ __forceinline__ void gl_lds16(const ushort* g, char* l) {
    __builtin_amdgcn_global_load_lds(
        (const __attribute__((address_space(1))) unsigned int*)(g),
        (__attribute__((address_space(3))) unsigned int*)(l), 16, 0, 0);
}

__device__ __forceinline__ ushort bf16_bits(float f) {
    __hip_bfloat16 h = __float2bfloat16(f);
    return *reinterpret_cast<ushort*>(&h);
}

// ---------------- fused producer: weights->bf16 pack + token-row gather/pack ----------------
__global__ void gather_prep(const float* __restrict__ emb,
                            const int* __restrict__ dids, const int* __restrict__ qids,
                            const float* __restrict__ w1, const float* __restrict__ w2,
                            const float* __restrict__ w3,
                            ushort* __restrict__ dpk, ushort* __restrict__ qpk,
                            ushort* __restrict__ wp) {
    int idx = blockIdx.x * 256 + threadIdx.x;
    if (idx < PREPW_N) {
        // ---- weights -> bf16, layout [o][j*320+c] ----
        const float* src;
        int k, rel, base;
        if (idx < 40960)        { k = 1; rel = idx;          src = w1; base = 0; }
        else if (idx < 122880)  { k = 2; rel = idx - 40960;  src = w2; base = 40960; }
        else                    { k = 3; rel = idx - 122880; src = w3; base = 122880; }
        int kd = 320 * k;
        int o = rel / kd;
        int jc = rel - o * kd;
        int j = jc / EMBP;
        int c = jc - j * EMBP;
        float f = (c < EMB) ? src[(o * EMB + c) * k + j] : 0.f;
        wp[base + rel] = bf16_bits(f);
        return;
    }
    idx -= PREPW_N;
    if (idx >= GATHER_N) return;
    // ---- gather token rows: fp32 emb -> packed bf16 [row][320] (doc + query + 2 zero rows) ----
    const int DROWS = NB * DL;
    int r = idx / 40;
    int c0 = (idx - r * 40) * 8;
    int rid;
    ushort* dst;
    if (r < DROWS) { rid = dids[r]; dst = dpk + (size_t)r * EMBP; }
    else if (r < DROWS + NB * QL) { rid = qids[r - DROWS]; dst = qpk + (size_t)(r - DROWS) * EMBP; }
    else {
        uint4 zz = {0u, 0u, 0u, 0u};
        *reinterpret_cast<uint4*>(qpk + (size_t)(r - DROWS) * EMBP + c0) = zz;
        return;
    }
    const float* erow = emb + (size_t)rid * EMB;
    ushort v[8];
    if (c0 + 8 <= EMB) {
        float4 f0 = *reinterpret_cast<const float4*>(erow + c0);
        float4 f1 = *reinterpret_cast<const float4*>(erow + c0 + 4);
        float fv[8] = {f0.x, f0.y, f0.z, f0.w, f1.x, f1.y, f1.z, f1.w};
#pragma unroll
        for (int i = 0; i < 8; ++i) v[i] = bf16_bits(fv[i]);
    } else {
#pragma unroll
        for (int i = 0; i < 8; ++i) {
            int c = c0 + i;
            v[i] = bf16_bits((c < EMB) ? erow[c] : 0.f);
        }
    }
    *reinterpret_cast<uint4*>(dst + c0) = *reinterpret_cast<uint4*>(v);
}

// ---------------- conv as one flattened GEMM: BK=32, LDS-staged, double-buffered, 4 blocks/CU ----------------
// Round 15 resolved: conv's WRITE 50.6MB is ALL logical output (hi+lo planes = 50.3MB; no
// spill), and conv is latency-bound at Occupancy 17% (2 blocks/CU, LDS-capped at 66KB).
// BK=32 halves LDS to 33KB -> 4 blocks/CU (2x TLP for a latency-bound kernel; barrier
// stalls in one block overlap other blocks' compute). With 64B LDS rows the wave's
// ds_read_b128 (quad q hits bank-group (row*4+q)&7, rows alternate parity) spreads
// EXACTLY 8 lanes/group -> conflict-free with a LINEAR layout; XOR swizzle removed.
// K-step order 2k/2k+1 == old step k's h=0/h=1 -> bit-identical accumulation.
// __launch_bounds__(256,4): VGPR cap 128 >> previous 88-reg allocation (safe margin).
__global__ __launch_bounds__(256, 4) void conv_mfma(const ushort* __restrict__ xpk,
                                                    const float* __restrict__ dmask,
                                                    const float* __restrict__ qmask,
                                                    const ushort* __restrict__ wp,
                                                    const float* __restrict__ b1,
                                                    const float* __restrict__ b2,
                                                    const float* __restrict__ b3,
                                                    ushort* __restrict__ dh,
                                                    ushort* __restrict__ dlo,
                                                    ushort* __restrict__ qh,
                                                    ushort* __restrict__ qlo) {
    __shared__ __align__(16) char smem[2][16512];    // per buffer: A 130x32 (8320B) + B 128x32 (8192B)

    const int tid = threadIdx.x;
    const int bid = blockIdx.x;
    // XCD-bijective swizzle: 792 = 8 * 99
    const int swz = (bid & 7) * (CONV_BLOCKS / 8) + (bid >> 3);
    const int z = swz % 3;
    const int tile = swz / 3;
    const int l0 = tile * 128;

    const int Kdim = EMBP * (z + 1);
    const int nk = 10 * (z + 1);                // K-steps of 32
    const ushort* wpk = wp + WPOFF_C[z];
    const float* bias = (z == 0) ? b1 : ((z == 1) ? b2 : b3);

    const int wave = tid >> 6;
    const int lane = tid & 63;
    const int l15 = lane & 15;
    const int quad = lane >> 4;
    const int wm = wave >> 1;
    const int wn = wave & 1;

    // staging map: lane -> (row = round*64 + wave*16 + lane/4, col = (lane&3)*8); linear LDS dest
    const int srow = lane >> 2;
    const int scol = (lane & 3) * 8;
    const ushort* a0 = xpk + (size_t)(l0 + wave * 16 + srow) * EMBP + scol;
    const ushort* at = xpk + (size_t)(l0 + 128 + srow) * EMBP + scol;   // tail rows 128..129 (lanes 0..7)
    const ushort* b0 = wpk + (size_t)(wave * 16 + srow) * Kdim + scol;

    auto stage = [&](int buf, int kk) {
        int jj = kk / 10;                       // tap index
        int coff = (kk - jj * 10) * 32;         // A col within the 320-wide token row
        int koff = kk * 32;                     // B col within Kdim
        char* abuf = smem[buf];
        char* bbuf = smem[buf] + 8320;
#pragma unroll
        for (int p = 0; p < 2; ++p)
            gl_lds16(a0 + p * (64 * EMBP) + coff, abuf + p * 4096 + wave * 1024);
        if (wave == 0 && lane < 8)
            gl_lds16(at + coff, abuf + 8192);
#pragma unroll
        for (int p = 0; p < 2; ++p)
            gl_lds16(b0 + (size_t)p * 64 * Kdim + koff, bbuf + p * 4096 + wave * 1024);
    };

    floatx4 acc[4][4];
#pragma unroll
    for (int i = 0; i < 4; ++i)
#pragma unroll
        for (int j = 0; j < 4; ++j) acc[i][j] = (floatx4)0.f;

    stage(0, 0);
    __syncthreads();

    int jjc = 0, ccc = 0;
    int buf = 0;
    for (int kk = 0; kk < nk; ++kk) {
        if (kk + 1 < nk) stage(buf ^ 1, kk + 1);
        const char* Ab = smem[buf];
        const char* Bb = smem[buf] + 8320;
        short8 af[4], bf[4];
#pragma unroll
        for (int i = 0; i < 4; ++i) {
            int ra = wm * 64 + i * 16 + l15 + jjc;
            int rb = wn * 64 + i * 16 + l15;
            af[i] = *reinterpret_cast<const short8*>(Ab + ra * 64 + quad * 16);
            bf[i] = *reinterpret_cast<const short8*>(Bb + rb * 64 + quad * 16);
        }
#pragma unroll
        for (int i = 0; i < 4; ++i)
#pragma unroll
            for (int j = 0; j < 4; ++j)
                acc[i][j] = __builtin_amdgcn_mfma_f32_16x16x32_bf16(af[i], bf[j], acc[i][j], 0, 0, 0);
        ++ccc;
        if (ccc == 10) { ccc = 0; ++jjc; }
        __syncthreads();
        buf ^= 1;
    }

    // ---- epilogue: bias + relu + row L2-norm + mask; emit bf16 hi/lo planes ----
    float (*rowsum)[128] = reinterpret_cast<float(*)[128]>(smem);
    float bv[4];
#pragma unroll
    for (int j = 0; j < 4; ++j) bv[j] = bias[wn * 64 + j * 16 + l15];
#pragma unroll
    for (int i = 0; i < 4; ++i)
#pragma unroll
        for (int r = 0; r < 4; ++r) {
            float p = 0.f;
#pragma unroll
            for (int j = 0; j < 4; ++j) {
                float y = fmaxf(acc[i][j][r] + bv[j], 0.f);
                acc[i][j][r] = y;
                p += y * y;
            }
#pragma unroll
            for (int m = 1; m < 16; m <<= 1) p += __shfl_xor(p, m, 64);
            if (l15 == 0) rowsum[wn][wm * 64 + i * 16 + quad * 4 + r] = p;
        }
    __syncthreads();

#pragma unroll
    for (int i = 0; i < 4; ++i) {
#pragma unroll
        for (int rr = 0; rr < 4; ++rr) {
            int rl = wm * 64 + i * 16 + quad * 4 + rr;
            int r = l0 + rl;                    // global combined row
            float tot = rowsum[0][rl] + rowsum[1][rl];
            float mv;
            ushort* hp;
            ushort* lp;
            if (r < NB * DL) {
                int l = r & (DL - 1);
                if (l >= DL - z) continue;
                mv = dmask[r];
                size_t base = (size_t)z * DPLANE + (size_t)r * OD;
                hp = dh + base; lp = dlo + base;
            } else {
                int t = r - NB * DL;
                int l = t & (QL - 1);
                if (l >= QL - z) continue;
                mv = qmask[t];
                size_t base = (size_t)z * QPLANE + (size_t)t * OD;
                hp = qh + base; lp = qlo + base;
            }
            float sc = mv / (sqrtf(tot) + 1e-13f);
            int cb = wn * 64 + l15;
#pragma unroll
            for (int j = 0; j < 4; ++j) {
                float v = acc[i][j][rr] * sc;
                __hip_bfloat16 h = __float2bfloat16(v);
                float hf = __bfloat162float(h);
                hp[cb + j * 16] = *reinterpret_cast<ushort*>(&h);
                __hip_bfloat16 l = __float2bfloat16(v - hf);
                lp[cb + j * 16] = *reinterpret_cast<ushort*>(&l);
            }
        }
    }
}

// ---------------- matcher: round-9 structure, qi-fast pp decode, __launch_bounds__(256,4) ----------------
// grid: (vtile=8, b=32, pp=9), block 256 = 4 waves.
// (256,4) is the UNIQUE good allocator point for this kernel, confirmed from both sides:
// no hint -> targets VGPR=36, spills the 21 bins (rounds 4/5: 130us); (256,6) -> VGPR=40,
// spills again (round 14: WRITE 75MB, 94.8us); (256,4) -> VGPR=52, WRITE=6MB, 50.5us.
// qi-fast pp decode (di=pp/3, qi=pp%3): V-sharing blocks 256 apart in dispatch order.
// Gaussian recurrence, 21 named-reg bins. Coalesced atomic commit.
__global__ __launch_bounds__(256, 4) void matcher_kernel(const ushort* __restrict__ qh_g,
                                                         const ushort* __restrict__ ql_g,
                                                         const ushort* __restrict__ vh_g,
                                                         const ushort* __restrict__ vl_g,
                                                         float* __restrict__ accb) {
    __shared__ __align__(16) float Sm[32 * 132];     // 16.9 KB S tile
    __shared__ float stageb[672];                    // 2.7 KB coalesced-commit staging

    const int tid = threadIdx.x;
    const int pp = blockIdx.z;
    const int b = blockIdx.y;
    const int v0 = blockIdx.x * 128;
    const int di = pp / 3;                // di SLOW
    const int qi = pp - di * 3;           // qi FAST: V-sharing blocks 256 apart
    const int Vk = 1024 - di;

    const ushort* qhb = qh_g + (size_t)qi * QPLANE + (size_t)b * (QL * OD);
    const ushort* qlb = ql_g + (size_t)qi * QPLANE + (size_t)b * (QL * OD);
    const ushort* vhb = vh_g + (size_t)di * DPLANE + (size_t)b * (DL * OD) + (size_t)v0 * OD;
    const ushort* vlb = vl_g + (size_t)di * DPLANE + (size_t)b * (DL * OD) + (size_t)v0 * OD;

    const int wave = tid >> 6;
    const int lane = tid & 63;
    const int l15 = lane & 15;
    const int quad = lane >> 4;

    floatx4 acc[2][2];
#pragma unroll
    for (int i = 0; i < 2; ++i)
#pragma unroll
        for (int j = 0; j < 2; ++j) acc[i][j] = (floatx4)0.f;

    // K = 128 as 4 windows of 32; lane's k-slice = quad*8 within each window.
#pragma unroll
    for (int kw = 0; kw < 4; ++kw) {
        const int ko = kw * 32 + quad * 8;
        short8 qh[2], ql[2], vh[2], vl[2];
#pragma unroll
        for (int i = 0; i < 2; ++i) {
            const int qr = i * 16 + l15;
            const int vr = wave * 32 + i * 16 + l15;
            qh[i] = *reinterpret_cast<const short8*>(qhb + qr * OD + ko);
            ql[i] = *reinterpret_cast<const short8*>(qlb + qr * OD + ko);
            vh[i] = *reinterpret_cast<const short8*>(vhb + (size_t)vr * OD + ko);
            vl[i] = *reinterpret_cast<const short8*>(vlb + (size_t)vr * OD + ko);
        }
#pragma unroll
        for (int i = 0; i < 2; ++i)
#pragma unroll
            for (int j = 0; j < 2; ++j) {
                acc[i][j] = __builtin_amdgcn_mfma_f32_16x16x32_bf16(qh[i], vh[j], acc[i][j], 0, 0, 0);
                acc[i][j] = __builtin_amdgcn_mfma_f32_16x16x32_bf16(qh[i], vl[j], acc[i][j], 0, 0, 0);
                acc[i][j] = __builtin_amdgcn_mfma_f32_16x16x32_bf16(ql[i], vh[j], acc[i][j], 0, 0, 0);
            }
    }

    // ---- S tile to LDS (stride 132 f32), poison v >= vmax with 1e4 ----
    const int vmax = min(128, Vk - v0);
#pragma unroll
    for (int i = 0; i < 2; ++i)
#pragma unroll
        for (int j = 0; j < 2; ++j)
#pragma unroll
            for (int r = 0; r < 4; ++r) {
                int q = i * 16 + quad * 4 + r;
                int v = wave * 32 + j * 16 + l15;
                float val = acc[i][j][r];
                if (v >= vmax) val = 1.0e4f;
                Sm[q * 132 + v] = val;
            }
    __syncthreads();

    // ---- gaussian phase: thread = (q = tid>>3, chunk c = tid&7 -> v in [c*16, c*16+16)) ----
    {
        const int q = tid >> 3;
        const int c = tid & 7;
        const float* srow = &Sm[q * 132 + c * 16];
        const float Am  = -72.13475204f;     // -log2e/(2*0.1^2)
        const float Am5 = -14.426950408f;    // 0.2*Am
        const float A0  = -721347.52f;       // -log2e/(2*0.001^2)
        const float C   = 0x1.0p-126f;

        float s00 = 0.f, s01 = 0.f, s02 = 0.f, s03 = 0.f, s04 = 0.f, s05 = 0.f,
              s06 = 0.f, s07 = 0.f, s08 = 0.f, s09 = 0.f, s10 = 0.f, s11 = 0.f,
              s12 = 0.f, s13 = 0.f, s14 = 0.f, s15 = 0.f, s16 = 0.f, s17 = 0.f,
              s18 = 0.f, s19 = 0.f, s20 = 0.f;

#define GACC(B) { B = __builtin_fmaf(tx, C, B); B = __builtin_fmaf(ty, C, B); \
                  B = __builtin_fmaf(tz, C, B); B = __builtin_fmaf(tw, C, B); }
#define GSTEP(B, g) { tx *= Rx * (g); ty *= Ry * (g); tz *= Rz * (g); tw *= Rw * (g); GACC(B) }

#pragma unroll
        for (int jj = 0; jj < 4; ++jj) {
            float4 s4 = *reinterpret_cast<const float4*>(srow + jj * 4);
            float dx = s4.x - 0.95f, dy = s4.y - 0.95f, dz = s4.z - 0.95f, dwv = s4.w - 0.95f;
            float tx = __builtin_exp2f(__builtin_fmaf(Am * dx, dx, 126.f));  // 2^126 * term_1
            float ty = __builtin_exp2f(__builtin_fmaf(Am * dy, dy, 126.f));
            float tz = __builtin_exp2f(__builtin_fmaf(Am * dz, dz, 126.f));
            float tw = __builtin_exp2f(__builtin_fmaf(Am * dwv, dwv, 126.f));
            float Rx = __builtin_exp2f(Am5 * dx);
            float Ry = __builtin_exp2f(Am5 * dy);
            float Rz = __builtin_exp2f(Am5 * dz);
            float Rw = __builtin_exp2f(Am5 * dwv);
            GACC(s01)
            GSTEP(s02, 6.0653066e-01f) GSTEP(s03, 2.2313016e-01f)
            GSTEP(s04, 8.2084999e-02f) GSTEP(s05, 3.0197383e-02f)
            GSTEP(s06, 1.1108997e-02f) GSTEP(s07, 4.0867714e-03f)
            GSTEP(s08, 1.5034391e-03f) GSTEP(s09, 5.5308438e-04f)
            GSTEP(s10, 2.0346837e-04f) GSTEP(s11, 7.4851830e-05f)
            GSTEP(s12, 2.7536450e-05f) GSTEP(s13, 1.0130095e-05f)
            GSTEP(s14, 3.7266532e-06f) GSTEP(s15, 1.3709590e-06f)
            GSTEP(s16, 5.0434766e-07f) GSTEP(s17, 1.8553914e-07f)
            GSTEP(s18, 6.8256033e-08f) GSTEP(s19, 2.5110699e-08f)
            GSTEP(s20, 9.2374496e-09f)
            float ex = s4.x - 1.f, ey = s4.y - 1.f, ez = s4.z - 1.f, ew = s4.w - 1.f;
            s00 += __builtin_exp2f((A0 * ex) * ex);
            s00 += __builtin_exp2f((A0 * ey) * ey);
            s00 += __builtin_exp2f((A0 * ez) * ez);
            s00 += __builtin_exp2f((A0 * ew) * ew);
        }
#undef GSTEP
#undef GACC

        // reduce over the 8 v-chunks (lane bits 0..2); c==0 stages to LDS
#define GRED(B) { B += __shfl_xor(B, 1, 64); B += __shfl_xor(B, 2, 64); B += __shfl_xor(B, 4, 64); }
        GRED(s00) GRED(s01) GRED(s02) GRED(s03) GRED(s04) GRED(s05) GRED(s06)
        GRED(s07) GRED(s08) GRED(s09) GRED(s10) GRED(s11) GRED(s12) GRED(s13)
        GRED(s14) GRED(s15) GRED(s16) GRED(s17) GRED(s18) GRED(s19) GRED(s20)
#undef GRED
        if (c == 0) {
            float* sp = &stageb[q * KNUM];
            sp[0]  = s00; sp[1]  = s01; sp[2]  = s02; sp[3]  = s03; sp[4]  = s04;
            sp[5]  = s05; sp[6]  = s06; sp[7]  = s07; sp[8]  = s08; sp[9]  = s09;
            sp[10] = s10; sp[11] = s11; sp[12] = s12; sp[13] = s13; sp[14] = s14;
            sp[15] = s15; sp[16] = s16; sp[17] = s17; sp[18] = s18; sp[19] = s19;
            sp[20] = s20;
        }
    }
    __syncthreads();

    // ---- coalesced atomic commit: 672 contiguous floats; logical pair id = qi*3+di ----
    {
        float* dst = &accb[((size_t)((qi * 3 + di) * NB + b) * QL) * KNUM];
        for (int i = tid; i < 32 * KNUM; i += 256)
            atomicAdd(dst + i, stageb[i]);
    }
}

// ---------------- finalize ----------------
__global__ void finalize_kernel(const float* __restrict__ accb,
                                const float* __restrict__ qmask,
                                const float* __restrict__ dw,
                                const float* __restrict__ db,
                                float* __restrict__ out) {
    __shared__ float prod[192];
    int b = blockIdx.x;
    int tid = threadIdx.x;
    if (tid < 189) {
        int pq = tid / 21;
        int t = tid - pq * 21;
        int qi = pq / 3;
        int Qk = 32 - qi;
        const float* ab = accb + ((pq * NB + b) * QL) * KNUM + t;
        float s = 0.f;
        for (int q = 0; q < Qk; ++q)
            s += logf(fmaxf(ab[q * KNUM], 1e-10f)) * qmask[b * QL + q];
        float lg = s * 0.01f;
        out[NB + b * 189 + tid] = lg;
        prod[tid] = lg * dw[tid];
    }
    __syncthreads();
    if (tid == 0) {
        float sc = db[0];
        for (int i = 0; i < 189; ++i) sc += prod[i];
        out[b] = sc;
    }
}

// ---------------- launcher ----------------
extern "C" void kernel_launch(void* const* d_in, const int* in_sizes, int n_in,
                              void* d_out, int out_size, void* d_ws, size_t ws_size,
                              hipStream_t stream) {
    const int* qids = (const int*)d_in[0];
    const float* qmask = (const float*)d_in[1];
    const int* dids = (const int*)d_in[2];
    const float* dmask = (const float*)d_in[3];
    const float* emb = (const float*)d_in[4];
    const float* w1 = (const float*)d_in[5];
    const float* b1 = (const float*)d_in[6];
    const float* w2 = (const float*)d_in[7];
    const float* b2 = (const float*)d_in[8];
    const float* w3 = (const float*)d_in[9];
    const float* b3 = (const float*)d_in[10];
    const float* dw = (const float*)d_in[11];
    const float* db = (const float*)d_in[12];
    float* out = (float*)d_out;
    float* ws = (float*)d_ws;

    ushort* wp  = (ushort*)(ws + WP_OFF);
    ushort* dpk = (ushort*)(ws + DPK_OFF);
    ushort* qpk = (ushort*)(ws + QPK_OFF);
    ushort* qh  = (ushort*)(ws + QH_OFF);
    ushort* qlo = (ushort*)(ws + QLO_OFF);
    ushort* dh  = (ushort*)(ws + DH_OFF);
    ushort* dlo = (ushort*)(ws + DLO_OFF);
    float* accb = ws + ACC_OFF;

    hipMemsetAsync(accb, 0, ACC_SZ * sizeof(float), stream);
    gather_prep<<<(PREPW_N + GATHER_N + 255) / 256, 256, 0, stream>>>(
        emb, dids, qids, w1, w2, w3, dpk, qpk, wp);

    conv_mfma<<<CONV_BLOCKS, 256, 0, stream>>>(dpk, dmask, qmask, wp, b1, b2, b3, dh, dlo, qh, qlo);

    matcher_kernel<<<dim3(8, NB, 9), 256, 0, stream>>>(qh, qlo, dh, dlo, accb);
    finalize_kernel<<<NB, 256, 0, stream>>>(accb, qmask, dw, db, out);
}

// Round 17
// 213.866 us; speedup vs baseline: 1.1271x; 1.0181x over previous
//
#include <hip/hip_runtime.h>
#include <hip/hip_bf16.h>
#include <math.h>

// ---------------- problem constants ----------------
#define NB 32
#define QL 32
#define DL 1024
#define EMB 300
#define EMBP 320            // padded K-dim per tap (zeros 300..319)
#define OD 128
#define KNUM 21
#define VOCAB 50000

typedef short short8 __attribute__((ext_vector_type(8)));
typedef float floatx4 __attribute__((ext_vector_type(4)));

// workspace layout (in float units)
static const size_t WP_OFF  = 0;           // packed bf16 weights: 245760 ushorts = 122880 fl
static const size_t DPK_OFF = 122880;      // packed doc bf16 [32*1024][320] = 5242880 fl
static const size_t QPK_OFF = 5365760;     // packed query bf16 [(1024+2)][320] = 164160 fl
// encoder outputs stored as SPLIT bf16 hi/lo planes
static const size_t QH_OFF  = 5529920;     // qenc hi: 3 * 32*32*128 us = 196608 fl
static const size_t QLO_OFF = 5726528;     // qenc lo
static const size_t DH_OFF  = 5923136;     // denc hi: 3 * 32*1024*128 us = 6291456 fl
static const size_t DLO_OFF = 12214592;    // denc lo
static const size_t ACC_OFF = 18506048;
static const int ACC_SZ = 9 * NB * QL * KNUM;          // 193536

#define QPLANE 131072      // ushorts per z-plane of qenc (32*32*128)
#define DPLANE 4194304     // ushorts per z-plane of denc (32*1024*128)

// combined packed rows: doc (32768) + query (1024) + 2 zero guard rows
#define MROWS (NB * DL + NB * QL)      // 33792 = 264 * 128 exactly
#define MTILES 264
#define CONV_BLOCKS (MTILES * 3)       // 792, divisible by 8 (XCD swizzle bijective)

#define PREPW_N 245760
#define GATHER_N ((MROWS + 2) * 40)
#define ACCZ_N (ACC_SZ / 4)            // 48384 float4 zero-stores

__device__ __constant__ int WPOFF_C[3] = {0, 40960, 122880};

__device__ __forceinline__ void gl_lds16(const ushort* g, char* l) {
    __builtin_amdgcn_global_load_lds(
        (const __attribute__((address_space(1))) unsigned int*)(g),
        (__attribute__((address_space(3))) unsigned int*)(l), 16, 0, 0);
}

__device__ __forceinline__ ushort bf16_bits(float f) {
    __hip_bfloat16 h = __float2bfloat16(f);
    return *reinterpret_cast<ushort*>(&h);
}

// ---------------- fused producer: weights pack + token gather + accb zero ----------------
__global__ void gather_prep(const float* __restrict__ emb,
                            const int* __restrict__ dids, const int* __restrict__ qids,
                            const float* __restrict__ w1, const float* __restrict__ w2,
                            const float* __restrict__ w3,
                            ushort* __restrict__ dpk, ushort* __restrict__ qpk,
                            ushort* __restrict__ wp, float* __restrict__ accb) {
    int idx = blockIdx.x * 256 + threadIdx.x;
    if (idx < PREPW_N) {
        // ---- weights -> bf16, layout [o][j*320+c] ----
        const float* src;
        int k, rel, base;
        if (idx < 40960)        { k = 1; rel = idx;          src = w1; base = 0; }
        else if (idx < 122880)  { k = 2; rel = idx - 40960;  src = w2; base = 40960; }
        else                    { k = 3; rel = idx - 122880; src = w3; base = 122880; }
        int kd = 320 * k;
        int o = rel / kd;
        int jc = rel - o * kd;
        int j = jc / EMBP;
        int c = jc - j * EMBP;
        float f = (c < EMB) ? src[(o * EMB + c) * k + j] : 0.f;
        wp[base + rel] = bf16_bits(f);
        return;
    }
    idx -= PREPW_N;
    if (idx < GATHER_N) {
        // ---- gather token rows: fp32 emb -> packed bf16 [row][320] ----
        const int DROWS = NB * DL;
        int r = idx / 40;
        int c0 = (idx - r * 40) * 8;
        int rid;
        ushort* dst;
        if (r < DROWS) { rid = dids[r]; dst = dpk + (size_t)r * EMBP; }
        else if (r < DROWS + NB * QL) { rid = qids[r - DROWS]; dst = qpk + (size_t)(r - DROWS) * EMBP; }
        else {
            uint4 zz = {0u, 0u, 0u, 0u};
            *reinterpret_cast<uint4*>(qpk + (size_t)(r - DROWS) * EMBP + c0) = zz;
            return;
        }
        const float* erow = emb + (size_t)rid * EMB;
        ushort v[8];
        if (c0 + 8 <= EMB) {
            float4 f0 = *reinterpret_cast<const float4*>(erow + c0);
            float4 f1 = *reinterpret_cast<const float4*>(erow + c0 + 4);
            float fv[8] = {f0.x, f0.y, f0.z, f0.w, f1.x, f1.y, f1.z, f1.w};
#pragma unroll
            for (int i = 0; i < 8; ++i) v[i] = bf16_bits(fv[i]);
        } else {
#pragma unroll
            for (int i = 0; i < 8; ++i) {
                int c = c0 + i;
                v[i] = bf16_bits((c < EMB) ? erow[c] : 0.f);
            }
        }
        *reinterpret_cast<uint4*>(dst + c0) = *reinterpret_cast<uint4*>(v);
        return;
    }
    idx -= GATHER_N;
    if (idx < ACCZ_N) {
        float4 z4 = {0.f, 0.f, 0.f, 0.f};
        reinterpret_cast<float4*>(accb)[idx] = z4;
    }
}

// ---------------- conv as one flattened GEMM: BK=32, LDS-staged, double-buffered, 4 blocks/CU ----------------
// BK=32 (round 16: conv 74.5 -> <48us; occupancy doubled). Linear LDS (64B rows are
// conflict-free for this read pattern). WRITE 50.6MB is all logical output (no spill).
__global__ __launch_bounds__(256, 4) void conv_mfma(const ushort* __restrict__ xpk,
                                                    const float* __restrict__ dmask,
                                                    const float* __restrict__ qmask,
                                                    const ushort* __restrict__ wp,
                                                    const float* __restrict__ b1,
                                                    const float* __restrict__ b2,
                                                    const float* __restrict__ b3,
                                                    ushort* __restrict__ dh,
                                                    ushort* __restrict__ dlo,
                                                    ushort* __restrict__ qh,
                                                    ushort* __restrict__ qlo) {
    __shared__ __align__(16) char smem[2][16512];    // per buffer: A 130x32 (8320B) + B 128x32 (8192B)

    const int tid = threadIdx.x;
    const int bid = blockIdx.x;
    // XCD-bijective swizzle: 792 = 8 * 99
    const int swz = (bid & 7) * (CONV_BLOCKS / 8) + (bid >> 3);
    const int z = swz % 3;
    const int tile = swz / 3;
    const int l0 = tile * 128;

    const int Kdim = EMBP * (z + 1);
    const int nk = 10 * (z + 1);                // K-steps of 32
    const ushort* wpk = wp + WPOFF_C[z];
    const float* bias = (z == 0) ? b1 : ((z == 1) ? b2 : b3);

    const int wave = tid >> 6;
    const int lane = tid & 63;
    const int l15 = lane & 15;
    const int quad = lane >> 4;
    const int wm = wave >> 1;
    const int wn = wave & 1;

    // staging map: lane -> (row = round*64 + wave*16 + lane/4, col = (lane&3)*8); linear LDS dest
    const int srow = lane >> 2;
    const int scol = (lane & 3) * 8;
    const ushort* a0 = xpk + (size_t)(l0 + wave * 16 + srow) * EMBP + scol;
    const ushort* at = xpk + (size_t)(l0 + 128 + srow) * EMBP + scol;   // tail rows 128..129 (lanes 0..7)
    const ushort* b0 = wpk + (size_t)(wave * 16 + srow) * Kdim + scol;

    auto stage = [&](int buf, int kk) {
        int jj = kk / 10;                       // tap index
        int coff = (kk - jj * 10) * 32;         // A col within the 320-wide token row
        int koff = kk * 32;                     // B col within Kdim
        char* abuf = smem[buf];
        char* bbuf = smem[buf] + 8320;
#pragma unroll
        for (int p = 0; p < 2; ++p)
            gl_lds16(a0 + p * (64 * EMBP) + coff, abuf + p * 4096 + wave * 1024);
        if (wave == 0 && lane < 8)
            gl_lds16(at + coff, abuf + 8192);
#pragma unroll
        for (int p = 0; p < 2; ++p)
            gl_lds16(b0 + (size_t)p * 64 * Kdim + koff, bbuf + p * 4096 + wave * 1024);
    };

    floatx4 acc[4][4];
#pragma unroll
    for (int i = 0; i < 4; ++i)
#pragma unroll
        for (int j = 0; j < 4; ++j) acc[i][j] = (floatx4)0.f;

    stage(0, 0);
    __syncthreads();

    int jjc = 0, ccc = 0;
    int buf = 0;
    for (int kk = 0; kk < nk; ++kk) {
        if (kk + 1 < nk) stage(buf ^ 1, kk + 1);
        const char* Ab = smem[buf];
        const char* Bb = smem[buf] + 8320;
        short8 af[4], bf[4];
#pragma unroll
        for (int i = 0; i < 4; ++i) {
            int ra = wm * 64 + i * 16 + l15 + jjc;
            int rb = wn * 64 + i * 16 + l15;
            af[i] = *reinterpret_cast<const short8*>(Ab + ra * 64 + quad * 16);
            bf[i] = *reinterpret_cast<const short8*>(Bb + rb * 64 + quad * 16);
        }
#pragma unroll
        for (int i = 0; i < 4; ++i)
#pragma unroll
            for (int j = 0; j < 4; ++j)
                acc[i][j] = __builtin_amdgcn_mfma_f32_16x16x32_bf16(af[i], bf[j], acc[i][j], 0, 0, 0);
        ++ccc;
        if (ccc == 10) { ccc = 0; ++jjc; }
        __syncthreads();
        buf ^= 1;
    }

    // ---- epilogue: bias + relu + row L2-norm + mask; emit bf16 hi/lo planes ----
    float (*rowsum)[128] = reinterpret_cast<float(*)[128]>(smem);
    float bv[4];
#pragma unroll
    for (int j = 0; j < 4; ++j) bv[j] = bias[wn * 64 + j * 16 + l15];
#pragma unroll
    for (int i = 0; i < 4; ++i)
#pragma unroll
        for (int r = 0; r < 4; ++r) {
            float p = 0.f;
#pragma unroll
            for (int j = 0; j < 4; ++j) {
                float y = fmaxf(acc[i][j][r] + bv[j], 0.f);
                acc[i][j][r] = y;
                p += y * y;
            }
#pragma unroll
            for (int m = 1; m < 16; m <<= 1) p += __shfl_xor(p, m, 64);
            if (l15 == 0) rowsum[wn][wm * 64 + i * 16 + quad * 4 + r] = p;
        }
    __syncthreads();

#pragma unroll
    for (int i = 0; i < 4; ++i) {
#pragma unroll
        for (int rr = 0; rr < 4; ++rr) {
            int rl = wm * 64 + i * 16 + quad * 4 + rr;
            int r = l0 + rl;                    // global combined row
            float tot = rowsum[0][rl] + rowsum[1][rl];
            float mv;
            ushort* hp;
            ushort* lp;
            if (r < NB * DL) {
                int l = r & (DL - 1);
                if (l >= DL - z) continue;
                mv = dmask[r];
                size_t base = (size_t)z * DPLANE + (size_t)r * OD;
                hp = dh + base; lp = dlo + base;
            } else {
                int t = r - NB * DL;
                int l = t & (QL - 1);
                if (l >= QL - z) continue;
                mv = qmask[t];
                size_t base = (size_t)z * QPLANE + (size_t)t * OD;
                hp = qh + base; lp = qlo + base;
            }
            float sc = mv / (sqrtf(tot) + 1e-13f);
            int cb = wn * 64 + l15;
#pragma unroll
            for (int j = 0; j < 4; ++j) {
                float v = acc[i][j][rr] * sc;
                __hip_bfloat16 h = __float2bfloat16(v);
                float hf = __bfloat162float(h);
                hp[cb + j * 16] = *reinterpret_cast<ushort*>(&h);
                __hip_bfloat16 l = __float2bfloat16(v - hf);
                lp[cb + j * 16] = *reinterpret_cast<ushort*>(&l);
            }
        }
    }
}

// ---------------- matcher: round-9 structure + kw software pipeline (2x loads in flight) ----------------
// grid: (vtile=8, b=32, pp=9), block 256 = 4 waves, qi-fast pp decode.
// Round 16 model: MFMA phase is HBM-LATENCY-bound (0.92 TB/s = ~8 in-flight 16B loads x
// 11 waves/CU at ~600ns); occupancy can't rise ((256,4) spill cliff proven rounds 4/5/14).
// Fix: depth-1 software pipeline over the 4 kw-windows -> 16 loads in flight per wave.
// +32 VGPR (52 -> ~85-100), safely under the 128 budget. Falsifier: WRITE>10MB = spill.
// Gaussian recurrence, 21 named-reg bins under __launch_bounds__(256,4). Coalesced commit.
__global__ __launch_bounds__(256, 4) void matcher_kernel(const ushort* __restrict__ qh_g,
                                                         const ushort* __restrict__ ql_g,
                                                         const ushort* __restrict__ vh_g,
                                                         const ushort* __restrict__ vl_g,
                                                         float* __restrict__ accb) {
    __shared__ __align__(16) float Sm[32 * 132];     // 16.9 KB S tile
    __shared__ float stageb[672];                    // 2.7 KB coalesced-commit staging

    const int tid = threadIdx.x;
    const int pp = blockIdx.z;
    const int b = blockIdx.y;
    const int v0 = blockIdx.x * 128;
    const int di = pp / 3;                // di SLOW
    const int qi = pp - di * 3;           // qi FAST: V-sharing blocks 256 apart
    const int Vk = 1024 - di;

    const ushort* qhb = qh_g + (size_t)qi * QPLANE + (size_t)b * (QL * OD);
    const ushort* qlb = ql_g + (size_t)qi * QPLANE + (size_t)b * (QL * OD);
    const ushort* vhb = vh_g + (size_t)di * DPLANE + (size_t)b * (DL * OD) + (size_t)v0 * OD;
    const ushort* vlb = vl_g + (size_t)di * DPLANE + (size_t)b * (DL * OD) + (size_t)v0 * OD;

    const int wave = tid >> 6;
    const int lane = tid & 63;
    const int l15 = lane & 15;
    const int quad = lane >> 4;

    floatx4 acc[2][2];
#pragma unroll
    for (int i = 0; i < 2; ++i)
#pragma unroll
        for (int j = 0; j < 2; ++j) acc[i][j] = (floatx4)0.f;

    // K = 128 as 4 windows of 32; frags double-buffered across windows (static parity idx).
    short8 qhf[2][2], qlf[2][2], vhf[2][2], vlf[2][2];

    auto loadw = [&](int kw, int bp) {
        const int ko = kw * 32 + quad * 8;
#pragma unroll
        for (int i = 0; i < 2; ++i) {
            const int qr = i * 16 + l15;
            const int vr = wave * 32 + i * 16 + l15;
            qhf[bp][i] = *reinterpret_cast<const short8*>(qhb + qr * OD + ko);
            qlf[bp][i] = *reinterpret_cast<const short8*>(qlb + qr * OD + ko);
            vhf[bp][i] = *reinterpret_cast<const short8*>(vhb + (size_t)vr * OD + ko);
            vlf[bp][i] = *reinterpret_cast<const short8*>(vlb + (size_t)vr * OD + ko);
        }
    };

    loadw(0, 0);
#pragma unroll
    for (int kw = 0; kw < 4; ++kw) {
        const int cur = kw & 1;
        if (kw + 1 < 4) loadw(kw + 1, cur ^ 1);
#pragma unroll
        for (int i = 0; i < 2; ++i)
#pragma unroll
            for (int j = 0; j < 2; ++j) {
                acc[i][j] = __builtin_amdgcn_mfma_f32_16x16x32_bf16(qhf[cur][i], vhf[cur][j], acc[i][j], 0, 0, 0);
                acc[i][j] = __builtin_amdgcn_mfma_f32_16x16x32_bf16(qhf[cur][i], vlf[cur][j], acc[i][j], 0, 0, 0);
                acc[i][j] = __builtin_amdgcn_mfma_f32_16x16x32_bf16(qlf[cur][i], vhf[cur][j], acc[i][j], 0, 0, 0);
            }
    }

    // ---- S tile to LDS (stride 132 f32), poison v >= vmax with 1e4 ----
    const int vmax = min(128, Vk - v0);
#pragma unroll
    for (int i = 0; i < 2; ++i)
#pragma unroll
        for (int j = 0; j < 2; ++j)
#pragma unroll
            for (int r = 0; r < 4; ++r) {
                int q = i * 16 + quad * 4 + r;
                int v = wave * 32 + j * 16 + l15;
                float val = acc[i][j][r];
                if (v >= vmax) val = 1.0e4f;
                Sm[q * 132 + v] = val;
            }
    __syncthreads();

    // ---- gaussian phase: thread = (q = tid>>3, chunk c = tid&7 -> v in [c*16, c*16+16)) ----
    {
        const int q = tid >> 3;
        const int c = tid & 7;
        const float* srow = &Sm[q * 132 + c * 16];
        const float Am  = -72.13475204f;     // -log2e/(2*0.1^2)
        const float Am5 = -14.426950408f;    // 0.2*Am
        const float A0  = -721347.52f;       // -log2e/(2*0.001^2)
        const float C   = 0x1.0p-126f;

        float s00 = 0.f, s01 = 0.f, s02 = 0.f, s03 = 0.f, s04 = 0.f, s05 = 0.f,
              s06 = 0.f, s07 = 0.f, s08 = 0.f, s09 = 0.f, s10 = 0.f, s11 = 0.f,
              s12 = 0.f, s13 = 0.f, s14 = 0.f, s15 = 0.f, s16 = 0.f, s17 = 0.f,
              s18 = 0.f, s19 = 0.f, s20 = 0.f;

#define GACC(B) { B = __builtin_fmaf(tx, C, B); B = __builtin_fmaf(ty, C, B); \
                  B = __builtin_fmaf(tz, C, B); B = __builtin_fmaf(tw, C, B); }
#define GSTEP(B, g) { tx *= Rx * (g); ty *= Ry * (g); tz *= Rz * (g); tw *= Rw * (g); GACC(B) }

#pragma unroll
        for (int jj = 0; jj < 4; ++jj) {
            float4 s4 = *reinterpret_cast<const float4*>(srow + jj * 4);
            float dx = s4.x - 0.95f, dy = s4.y - 0.95f, dz = s4.z - 0.95f, dwv = s4.w - 0.95f;
            float tx = __builtin_exp2f(__builtin_fmaf(Am * dx, dx, 126.f));  // 2^126 * term_1
            float ty = __builtin_exp2f(__builtin_fmaf(Am * dy, dy, 126.f));
            float tz = __builtin_exp2f(__builtin_fmaf(Am * dz, dz, 126.f));
            float tw = __builtin_exp2f(__builtin_fmaf(Am * dwv, dwv, 126.f));
            float Rx = __builtin_exp2f(Am5 * dx);
            float Ry = __builtin_exp2f(Am5 * dy);
            float Rz = __builtin_exp2f(Am5 * dz);
            float Rw = __builtin_exp2f(Am5 * dwv);
            GACC(s01)
            GSTEP(s02, 6.0653066e-01f) GSTEP(s03, 2.2313016e-01f)
            GSTEP(s04, 8.2084999e-02f) GSTEP(s05, 3.0197383e-02f)
            GSTEP(s06, 1.1108997e-02f) GSTEP(s07, 4.0867714e-03f)
            GSTEP(s08, 1.5034391e-03f) GSTEP(s09, 5.5308438e-04f)
            GSTEP(s10, 2.0346837e-04f) GSTEP(s11, 7.4851830e-05f)
            GSTEP(s12, 2.7536450e-05f) GSTEP(s13, 1.0130095e-05f)
            GSTEP(s14, 3.7266532e-06f) GSTEP(s15, 1.3709590e-06f)
            GSTEP(s16, 5.0434766e-07f) GSTEP(s17, 1.8553914e-07f)
            GSTEP(s18, 6.8256033e-08f) GSTEP(s19, 2.5110699e-08f)
            GSTEP(s20, 9.2374496e-09f)
            float ex = s4.x - 1.f, ey = s4.y - 1.f, ez = s4.z - 1.f, ew = s4.w - 1.f;
            s00 += __builtin_exp2f((A0 * ex) * ex);
            s00 += __builtin_exp2f((A0 * ey) * ey);
            s00 += __builtin_exp2f((A0 * ez) * ez);
            s00 += __builtin_exp2f((A0 * ew) * ew);
        }
#undef GSTEP
#undef GACC

        // reduce over the 8 v-chunks (lane bits 0..2); c==0 stages to LDS
#define GRED(B) { B += __shfl_xor(B, 1, 64); B += __shfl_xor(B, 2, 64); B += __shfl_xor(B, 4, 64); }
        GRED(s00) GRED(s01) GRED(s02) GRED(s03) GRED(s04) GRED(s05) GRED(s06)
        GRED(s07) GRED(s08) GRED(s09) GRED(s10) GRED(s11) GRED(s12) GRED(s13)
        GRED(s14) GRED(s15) GRED(s16) GRED(s17) GRED(s18) GRED(s19) GRED(s20)
#undef GRED
        if (c == 0) {
            float* sp = &stageb[q * KNUM];
            sp[0]  = s00; sp[1]  = s01; sp[2]  = s02; sp[3]  = s03; sp[4]  = s04;
            sp[5]  = s05; sp[6]  = s06; sp[7]  = s07; sp[8]  = s08; sp[9]  = s09;
            sp[10] = s10; sp[11] = s11; sp[12] = s12; sp[13] = s13; sp[14] = s14;
            sp[15] = s15; sp[16] = s16; sp[17] = s17; sp[18] = s18; sp[19] = s19;
            sp[20] = s20;
        }
    }
    __syncthreads();

    // ---- coalesced atomic commit: 672 contiguous floats; logical pair id = qi*3+di ----
    {
        float* dst = &accb[((size_t)((qi * 3 + di) * NB + b) * QL) * KNUM];
        for (int i = tid; i < 32 * KNUM; i += 256)
            atomicAdd(dst + i, stageb[i]);
    }
}

// ---------------- finalize ----------------
__global__ void finalize_kernel(const float* __restrict__ accb,
                                const float* __restrict__ qmask,
                                const float* __restrict__ dw,
                                const float* __restrict__ db,
                                float* __restrict__ out) {
    __shared__ float prod[192];
    int b = blockIdx.x;
    int tid = threadIdx.x;
    if (tid < 189) {
        int pq = tid / 21;
        int t = tid - pq * 21;
        int qi = pq / 3;
        int Qk = 32 - qi;
        const float* ab = accb + ((pq * NB + b) * QL) * KNUM + t;
        float s = 0.f;
        for (int q = 0; q < Qk; ++q)
            s += logf(fmaxf(ab[q * KNUM], 1e-10f)) * qmask[b * QL + q];
        float lg = s * 0.01f;
        out[NB + b * 189 + tid] = lg;
        prod[tid] = lg * dw[tid];
    }
    __syncthreads();
    if (tid == 0) {
        float sc = db[0];
        for (int i = 0; i < 189; ++i) sc += prod[i];
        out[b] = sc;
    }
}

// ---------------- launcher ----------------
extern "C" void kernel_launch(void* const* d_in, const int* in_sizes, int n_in,
                              void* d_out, int out_size, void* d_ws, size_t ws_size,
                              hipStream_t stream) {
    const int* qids = (const int*)d_in[0];
    const float* qmask = (const float*)d_in[1];
    const int* dids = (const int*)d_in[2];
    const float* dmask = (const float*)d_in[3];
    const float* emb = (const float*)d_in[4];
    const float* w1 = (const float*)d_in[5];
    const float* b1 = (const float*)d_in[6];
    const float* w2 = (const float*)d_in[7];
    const float* b2 = (const float*)d_in[8];
    const float* w3 = (const float*)d_in[9];
    const float* b3 = (const float*)d_in[10];
    const float* dw = (const float*)d_in[11];
    const float* db = (const float*)d_in[12];
    float* out = (float*)d_out;
    float* ws = (float*)d_ws;

    ushort* wp  = (ushort*)(ws + WP_OFF);
    ushort* dpk = (ushort*)(ws + DPK_OFF);
    ushort* qpk = (ushort*)(ws + QPK_OFF);
    ushort* qh  = (ushort*)(ws + QH_OFF);
    ushort* qlo = (ushort*)(ws + QLO_OFF);
    ushort* dh  = (ushort*)(ws + DH_OFF);
    ushort* dlo = (ushort*)(ws + DLO_OFF);
    float* accb = ws + ACC_OFF;

    gather_prep<<<(PREPW_N + GATHER_N + ACCZ_N + 255) / 256, 256, 0, stream>>>(
        emb, dids, qids, w1, w2, w3, dpk, qpk, wp, accb);

    conv_mfma<<<CONV_BLOCKS, 256, 0, stream>>>(dpk, dmask, qmask, wp, b1, b2, b3, dh, dlo, qh, qlo);

    matcher_kernel<<<dim3(8, NB, 9), 256, 0, stream>>>(qh, qlo, dh, dlo, accb);
    finalize_kernel<<<NB, 256, 0, stream>>>(accb, qmask, dw, db, out);
}